// Round 7
// baseline (247.846 us; speedup 1.0000x reference)
//
#include <hip/hip_runtime.h>
#include <hip/hip_bf16.h>
#include <stdint.h>

// Problem constants
#define BT   768
#define NN   512
#define DIN  64
#define HID  128
#define EMB  16
#define SLOPE 0.01f

typedef __attribute__((ext_vector_type(8))) short bf16x8;   // 8 bf16 (4 VGPRs)
typedef __attribute__((ext_vector_type(4))) float f32x4;    // MFMA C/D frag
typedef __attribute__((ext_vector_type(4))) short short4v;

__device__ __forceinline__ short f2bf(float f) {            // fp32 -> bf16 RNE
    uint32_t u = __float_as_uint(f);
    u += 0x7fff + ((u >> 16) & 1);
    return (short)(u >> 16);
}
__device__ __forceinline__ float bf2f(short s) {
    return __uint_as_float(((uint32_t)(unsigned short)s) << 16);
}

// ---------------- workspace layout (bytes) ----------------
// Hypernetwork weights are NEVER materialized: consumers combine the tiny
// (L2-resident) pool tensors inline. Only pools + h2 live in the workspace.
static const size_t OFF_PTT  = 0;           // pool_tem^T bf16 [d][o=128][i=128] = 512 KB
static const size_t OFF_PTS2 = 524288;      // P^T bf16 [d][o=128][k=64]; P[d]=W1@pool_spa[d]
static const size_t OFF_QB   = 786432;      // qb[d][o] = bp_spa[d][o] + b1@pool_spa[d], fp32 [16][128]
static const size_t OFF_H2   = 1048576;     // bf16 [n][R][o] = 100.7 MB

// ---------------------------------------------------------------------------
// k_prep (82 blocks, unchanged):
//   b 0..63  : transpose pool_tem -> ptt bf16 [d][o][i]
//   b 64..65 : qb[d][o] = bp_spa[d][o] + sum_i b1[i]*pool_spa[d][i][o]
//   b 66..81 : pts2: P^T[d][o][k] = sum_i pool_spa[d][i][o]*W1[k][i]  (MFMA)
// ---------------------------------------------------------------------------
__global__ __launch_bounds__(256)
void k_prep(const float* __restrict__ pool_spa, const float* __restrict__ pool_tem,
            const float* __restrict__ W1, const float* __restrict__ b1,
            const float* __restrict__ bp_spa,
            short* __restrict__ ptt, short* __restrict__ pts2,
            float* __restrict__ qb)
{
    const int b = blockIdx.x, t = threadIdx.x;
    __shared__ short smem[26112];            // 52.2 KB max (pts2 branch)

    if (b < 64) {                            // ---- pool_tem transpose ----
        const int d = b >> 2, o0 = (b & 3) * 32;
        short* s = smem;                     // [32][136]
        #pragma unroll
        for (int c = 0; c < 16; ++c) {
            int e = c * 256 + t;
            int i = e >> 5, oo = e & 31;
            s[oo * 136 + i] = f2bf(pool_tem[(d * HID + i) * HID + o0 + oo]);
        }
        __syncthreads();
        #pragma unroll
        for (int c = 0; c < 8; ++c) {
            int e = c * 256 + t;
            int oo = e >> 6, ii = (e & 63) * 2;
            uint32_t lo = (unsigned short)s[oo * 136 + ii];
            uint32_t hi = (unsigned short)s[oo * 136 + ii + 1];
            ((uint32_t*)ptt)[((d * HID + o0 + oo) * HID + ii) >> 1] = lo | (hi << 16);
        }
        return;
    }
    if (b < 66) {                            // ---- qb table ----
        const int dbase = (b - 64) * 8;
        if (t < 128) {
            float a[8];
            #pragma unroll
            for (int dd = 0; dd < 8; ++dd) a[dd] = bp_spa[(dbase + dd) * HID + t];
            for (int i = 0; i < HID; ++i) {
                float bv = b1[i];
                #pragma unroll
                for (int dd = 0; dd < 8; ++dd)
                    a[dd] += bv * pool_spa[((dbase + dd) * HID + i) * HID + t];
            }
            #pragma unroll
            for (int dd = 0; dd < 8; ++dd) qb[(dbase + dd) * HID + t] = a[dd];
        }
        return;
    }
    // ---- pts2: P^T[d] = (pool_spa[d]^T @ W1^T), out [o=128][k=64], contraction i=128
    {
        const int d = b - 66;
        const int wave = t >> 6, lane = t & 63, quad = lane >> 4, l15 = lane & 15;
        const int m0 = wave * 32;
        short* sPT  = smem;                  // [128][136] pool^T bf16 [o][i]
        short* sW1b = smem + 128 * 136;      // [64][136]  W1 bf16 [k][i]
        #pragma unroll
        for (int c = 0; c < 64; ++c) {
            int idx = c * 256 + t;
            int i = idx >> 7, o = idx & 127;
            sPT[o * 136 + i] = f2bf(pool_spa[(d * HID + i) * HID + o]);
        }
        #pragma unroll
        for (int c = 0; c < 32; ++c) {
            int idx = c * 256 + t;           // W1 is [k=64][i=128] row-major
            sW1b[(idx >> 7) * 136 + (idx & 127)] = f2bf(W1[idx]);
        }
        __syncthreads();
        f32x4 acc[2][4] = {};
        #pragma unroll
        for (int kc = 0; kc < 4; ++kc) {
            bf16x8 a0 = *(const bf16x8*)(sPT + (m0 + l15) * 136 + kc * 32 + quad * 8);
            bf16x8 a1 = *(const bf16x8*)(sPT + (m0 + 16 + l15) * 136 + kc * 32 + quad * 8);
            #pragma unroll
            for (int tc = 0; tc < 4; ++tc) {
                bf16x8 bb = *(const bf16x8*)(sW1b + (tc * 16 + l15) * 136 + kc * 32 + quad * 8);
                acc[0][tc] = __builtin_amdgcn_mfma_f32_16x16x32_bf16(a0, bb, acc[0][tc], 0, 0, 0);
                acc[1][tc] = __builtin_amdgcn_mfma_f32_16x16x32_bf16(a1, bb, acc[1][tc], 0, 0, 0);
            }
        }
        __syncthreads();
        short* sO = smem;                    // reuse: [128][72]
        #pragma unroll
        for (int tr = 0; tr < 2; ++tr)
            #pragma unroll
            for (int tc = 0; tc < 4; ++tc)
                #pragma unroll
                for (int r = 0; r < 4; ++r)
                    sO[(m0 + tr * 16 + quad * 4 + r) * 72 + tc * 16 + l15] = f2bf(acc[tr][tc][r]);
        __syncthreads();
        #pragma unroll
        for (int c = 0; c < 4; ++c) {
            int idx = c * 256 + t;
            int row = idx >> 3, ko = (idx & 7) * 8;
            *(bf16x8*)(pts2 + (size_t)d * 8192 + row * 64 + ko) =
                *(const bf16x8*)(sO + row * 72 + ko);
        }
    }
}

// ---------------------------------------------------------------------------
// k_spatial v7: 2 n per block -> eb reads are 512 B contiguous spans
// (vs 256 B in v6) at non-issue VGPR cost; weights in LDS (occupancy
// controlled, unlike v5). Chunk = 32 r, 12 chunks, 2 barriers/chunk.
// Grid (256 n-pairs, 2 r-halves of 384) = 512 blocks = 2/CU.
// LDS 72,704 B -> 2 blocks/CU. wcomb generated inline per n (per wave-pair).
// ---------------------------------------------------------------------------
__global__ __launch_bounds__(256)
void k_spatial(const float* __restrict__ eb, const short* __restrict__ pts2,
               const float* __restrict__ qb, const float* __restrict__ node_eb,
               short* __restrict__ h2)
{
    const int n0 = blockIdx.x * 2;           // 2 n per block
    const int Rbase = blockIdx.y * 384;      // 12 chunks of 32 rows
    const int t = threadIdx.x;
    const int wave = t >> 6, lane = t & 63, quad = lane >> 4, l15 = lane & 15;
    const int wn = wave >> 1;                // which n this wave computes
    const int mrow = (wave & 1) * 16;        // row-half within 32-row chunk

    __shared__ short sW[2][128 * 72];        // wcomb per n          36,864 B
    __shared__ short sEb[2][2][32 * 72];     // eb chunk dbuf x 2n   18,432 B
    __shared__ short sOut[2][32 * 136];      // out staging per n    17,408 B

    const float* ebn = eb + (size_t)n0 * DIN;

    // ---- issue chunk-0 eb loads first: 512 B spans (2n x 64k fp32) ----
    float4 ev[4];
    #pragma unroll
    for (int c = 0; c < 4; ++c) {
        int idx = c * 256 + t;
        int r = idx >> 5, f4 = idx & 31;
        ev[c] = *(const float4*)(ebn + (size_t)(Rbase + r) * (NN * DIN) + f4 * 4);
    }
    // ---- node embedding for this wave's n ----
    float ne[EMB];
    #pragma unroll
    for (int d = 0; d < EMB; ++d) ne[d] = node_eb[(n0 + wn) * EMB + d];
    // ---- combined bias: bsr = sum_d ne[d] * qb[d][col] ----
    float bsr[8];
    #pragma unroll
    for (int tc = 0; tc < 8; ++tc) {
        int col = tc * 16 + l15;
        float a = 0.f;
        #pragma unroll
        for (int d = 0; d < EMB; ++d) a += ne[d] * qb[d * HID + col];
        bsr[tc] = a;
    }
    // ---- inline wcomb for this wave-pair's n: sW[wn][o][k] ----
    {
        const int pt = t & 127;              // thread within wave-pair
        #pragma unroll
        for (int c = 0; c < 8; ++c) {
            int cell = c * 128 + pt;         // 1024 cells: [o=128][k8=8]
            int o = cell >> 3, k0 = (cell & 7) * 8;
            float a8[8] = {};
            #pragma unroll
            for (int d = 0; d < EMB; ++d) {
                bf16x8 pv = *(const bf16x8*)(pts2 + (size_t)d * 8192 + o * 64 + k0);
                #pragma unroll
                for (int e = 0; e < 8; ++e) a8[e] += ne[d] * bf2f(pv[e]);
            }
            bf16x8 w;
            #pragma unroll
            for (int e = 0; e < 8; ++e) w[e] = f2bf(a8[e]);
            *(bf16x8*)(&sW[wn][o * 72 + k0]) = w;
        }
    }
    // ---- stage eb chunk 0 (split by n) ----
    #pragma unroll
    for (int c = 0; c < 4; ++c) {
        int idx = c * 256 + t;
        int r = idx >> 5, nn = (idx & 31) >> 4, k4 = (idx & 15) * 4;
        short4v s;
        s.x = f2bf(ev[c].x); s.y = f2bf(ev[c].y);
        s.z = f2bf(ev[c].z); s.w = f2bf(ev[c].w);
        *(short4v*)(&sEb[0][nn][r * 72 + k4]) = s;
    }
    __syncthreads();

    // ---- main loop over 12 chunks of 32 rows ----
    for (int ch = 0; ch < 12; ++ch) {
        const int cur = ch & 1, nxt = cur ^ 1;
        if (ch < 11) {                       // prefetch next chunk (512 B spans)
            #pragma unroll
            for (int c = 0; c < 4; ++c) {
                int idx = c * 256 + t;
                int r = (ch + 1) * 32 + (idx >> 5), f4 = idx & 31;
                ev[c] = *(const float4*)(ebn + (size_t)(Rbase + r) * (NN * DIN) + f4 * 4);
            }
        }
        // GEMM: per wave [16r x 64k] @ [64k x 128o] of its n
        f32x4 acc[8] = {};
        #pragma unroll
        for (int kc = 0; kc < 2; ++kc) {
            bf16x8 a = *(const bf16x8*)(&sEb[cur][wn][(mrow + l15) * 72 + kc * 32 + quad * 8]);
            #pragma unroll
            for (int tc = 0; tc < 8; ++tc) {
                bf16x8 bfr = *(const bf16x8*)(&sW[wn][(tc * 16 + l15) * 72 + kc * 32 + quad * 8]);
                acc[tc] = __builtin_amdgcn_mfma_f32_16x16x32_bf16(a, bfr, acc[tc], 0, 0, 0);
            }
        }
        // epilogue: bias + leaky -> sOut[wn]
        #pragma unroll
        for (int tc = 0; tc < 8; ++tc) {
            int col = tc * 16 + l15;
            #pragma unroll
            for (int r = 0; r < 4; ++r) {
                float v = acc[tc][r] + bsr[tc];
                v = (v >= 0.f) ? v : SLOPE * v;
                sOut[wn][(mrow + quad * 4 + r) * 136 + col] = f2bf(v);
            }
        }
        // stage next chunk (vmcnt wait lands here)
        if (ch < 11) {
            #pragma unroll
            for (int c = 0; c < 4; ++c) {
                int idx = c * 256 + t;
                int r = idx >> 5, nn = (idx & 31) >> 4, k4 = (idx & 15) * 4;
                short4v s;
                s.x = f2bf(ev[c].x); s.y = f2bf(ev[c].y);
                s.z = f2bf(ev[c].z); s.w = f2bf(ev[c].w);
                *(short4v*)(&sEb[nxt][nn][r * 72 + k4]) = s;
            }
        }
        __syncthreads();                     // sOut + sEb[nxt] visible
        // store chunk: per n a contiguous 8 KB burst ([n][R][o] layout)
        #pragma unroll
        for (int c = 0; c < 4; ++c) {
            int idx = c * 256 + t;
            int ni = idx >> 9, row = (idx & 511) >> 4, col8 = (idx & 15) * 8;
            *(bf16x8*)(h2 + (size_t)(n0 + ni) * (BT * HID)
                          + (size_t)(Rbase + ch * 32 + row) * HID + col8) =
                *(const bf16x8*)(&sOut[ni][row * 136 + col8]);
        }
        __syncthreads();                     // sOut reads done before next epilogue
    }
}

// ---------------------------------------------------------------------------
// k_temporal v2 (unchanged): persistent per-R, wtem/btem generated inline.
// ---------------------------------------------------------------------------
__global__ __launch_bounds__(256, 3)
void k_temporal(const short* __restrict__ h2, const short* __restrict__ ptt,
                const float* __restrict__ bp_tem, const float* __restrict__ time_eb,
                const float* __restrict__ W3, const float* __restrict__ b3,
                float* __restrict__ out)
{
    const int R = blockIdx.x;
    const int t = threadIdx.x;
    const int wave = t >> 6, lane = t & 63, quad = lane >> 4, l15 = lane & 15;
    const int m0 = wave * 16;

    __shared__ short sWt[128 * 136];     // 34,816 B
    __shared__ short sH2[64 * 136];      // 17,408 B

    const short* hb = h2 + (size_t)R * HID;           // + n*BT*HID walks n

    bf16x8 hreg[4];
    #pragma unroll
    for (int c = 0; c < 4; ++c) {
        int idx = c * 256 + t;
        hreg[c] = *(const bf16x8*)(hb + (size_t)(idx >> 4) * (BT * HID) + (idx & 15) * 8);
    }
    float te[EMB];
    #pragma unroll
    for (int d = 0; d < EMB; ++d) te[d] = time_eb[R * EMB + d];
    #pragma unroll
    for (int c = 0; c < 8; ++c) {
        int idx = c * 256 + t;
        int o = idx >> 4, i0 = (idx & 15) * 8;
        float a8[8] = {};
        #pragma unroll
        for (int d = 0; d < EMB; ++d) {
            bf16x8 pv = *(const bf16x8*)(ptt + (size_t)d * 16384 + o * 128 + i0);
            #pragma unroll
            for (int e = 0; e < 8; ++e) a8[e] += te[d] * bf2f(pv[e]);
        }
        bf16x8 w;
        #pragma unroll
        for (int e = 0; e < 8; ++e) w[e] = f2bf(a8[e]);
        *(bf16x8*)(sWt + o * 136 + i0) = w;
    }
    float btr[8], w3r0[8], w3r1[8];
    #pragma unroll
    for (int tc = 0; tc < 8; ++tc) {
        int o = tc * 16 + l15;
        float a = 0.f;
        #pragma unroll
        for (int d = 0; d < EMB; ++d) a += te[d] * bp_tem[d * HID + o];
        btr[tc] = a;
        w3r0[tc] = W3[2 * o]; w3r1[tc] = W3[2 * o + 1];
    }
    const float b30 = b3[0], b31 = b3[1];

    #pragma unroll
    for (int c = 0; c < 4; ++c) {
        int idx = c * 256 + t;
        *(bf16x8*)(sH2 + (idx >> 4) * 136 + (idx & 15) * 8) = hreg[c];
    }
    __syncthreads();

    for (int nt = 0; nt < 8; ++nt) {
        if (nt < 7) {
            #pragma unroll
            for (int c = 0; c < 4; ++c) {
                int idx = c * 256 + t;
                hreg[c] = *(const bf16x8*)(hb + (size_t)((nt + 1) * 64 + (idx >> 4)) * (BT * HID) + (idx & 15) * 8);
            }
        }
        f32x4 acc[8] = {};
        #pragma unroll
        for (int kc = 0; kc < 4; ++kc) {
            bf16x8 a = *(const bf16x8*)(sH2 + (m0 + l15) * 136 + kc * 32 + quad * 8);
            #pragma unroll
            for (int tc = 0; tc < 8; ++tc) {
                bf16x8 b = *(const bf16x8*)(sWt + (tc * 16 + l15) * 136 + kc * 32 + quad * 8);
                acc[tc] = __builtin_amdgcn_mfma_f32_16x16x32_bf16(a, b, acc[tc], 0, 0, 0);
            }
        }
        float pl[4][2] = {};
        #pragma unroll
        for (int tc = 0; tc < 8; ++tc) {
            #pragma unroll
            for (int r = 0; r < 4; ++r) {
                float v = acc[tc][r] + btr[tc];
                v = (v >= 0.f) ? v : SLOPE * v;
                pl[r][0] += v * w3r0[tc];
                pl[r][1] += v * w3r1[tc];
            }
        }
        #pragma unroll
        for (int m = 1; m <= 8; m <<= 1)
            #pragma unroll
            for (int r = 0; r < 4; ++r) {
                pl[r][0] += __shfl_xor(pl[r][0], m);
                pl[r][1] += __shfl_xor(pl[r][1], m);
            }
        if (l15 == 0) {
            #pragma unroll
            for (int r = 0; r < 4; ++r) {
                int nrow = nt * 64 + m0 + quad * 4 + r;
                *(float2*)(out + ((size_t)R * NN + nrow) * 2) =
                    make_float2(pl[r][0] + b30, pl[r][1] + b31);
            }
        }
        __syncthreads();
        if (nt < 7) {
            #pragma unroll
            for (int c = 0; c < 4; ++c) {
                int idx = c * 256 + t;
                *(bf16x8*)(sH2 + (idx >> 4) * 136 + (idx & 15) * 8) = hreg[c];
            }
            __syncthreads();
        }
    }
}

extern "C" void kernel_launch(void* const* d_in, const int* in_sizes, int n_in,
                              void* d_out, int out_size, void* d_ws, size_t ws_size,
                              hipStream_t stream) {
    const float* eb        = (const float*)d_in[0];
    const float* time_eb   = (const float*)d_in[1];
    const float* node_eb   = (const float*)d_in[2];
    const float* W1        = (const float*)d_in[3];
    const float* b1        = (const float*)d_in[4];
    const float* W3        = (const float*)d_in[5];
    const float* b3        = (const float*)d_in[6];
    const float* pool_spa  = (const float*)d_in[7];
    const float* bpool_spa = (const float*)d_in[8];
    const float* pool_tem  = (const float*)d_in[9];
    const float* bpool_tem = (const float*)d_in[10];
    float* out = (float*)d_out;

    char* ws = (char*)d_ws;
    short* ptt  = (short*)(ws + OFF_PTT);
    short* pts2 = (short*)(ws + OFF_PTS2);
    float* qb   = (float*)(ws + OFF_QB);
    short* h2   = (short*)(ws + OFF_H2);

    k_prep<<<82, 256, 0, stream>>>(pool_spa, pool_tem, W1, b1, bpool_spa,
                                   ptt, pts2, qb);
    k_spatial<<<dim3(256, 2), 256, 0, stream>>>(eb, pts2, qb, node_eb, h2);
    k_temporal<<<dim3(BT), 256, 0, stream>>>(h2, ptt, bpool_tem, time_eb, W3, b3, out);
}